// Round 10
// baseline (155.343 us; speedup 1.0000x reference)
//
#include <hip/hip_runtime.h>

#define T_SEQ 512
#define EMB 32
#define HID 128
#define LDSW 160     // fallback row stride
#define PF 4         // xw prefetch ring depth
#define GROWS 64     // bt-rows per GEMM block -> 4096 blocks

typedef __attribute__((ext_vector_type(8))) short short8;   // 8 bf16
typedef __attribute__((ext_vector_type(4))) float f32x4;

__device__ __forceinline__ short f2bf(float f) {
  union { float f; unsigned u; } v; v.f = f;
  unsigned r = (v.u + 0x7FFFu + ((v.u >> 16) & 1u)) >> 16;  // RNE
  return (short)r;
}

__device__ __forceinline__ float bf2f(unsigned short u) {
  union { unsigned u; float f; } c; c.u = ((unsigned)u) << 16; return c.f;
}

__device__ __forceinline__ float tanh_fast(float a) {
  float e = __expf(2.0f * a);
  return 1.0f - 2.0f * __builtin_amdgcn_rcpf(e + 1.0f);
}

#define MFMA(a, b, c) __builtin_amdgcn_mfma_f32_16x16x32_bf16((a), (b), (c), 0, 0, 0)

// ---------------- Kernel 1: xw[bt][c] = x[bt][:] @ Wx + bh  (bf16) ----------------
__global__ __launch_bounds__(256) void xw_gemm_kernel(
    const float* __restrict__ x, const float* __restrict__ Wx,
    const float* __restrict__ bh, unsigned short* __restrict__ xw) {
  const int tid = threadIdx.x;
  const int wid = tid >> 6;
  const int lane = tid & 63;
  const int l4 = lane >> 4, lm = lane & 15;
  const int colbase = wid * 32;

  short8 wxf[2]; float bv[2];
#pragma unroll
  for (int nt = 0; nt < 2; ++nt) {
    const int col = colbase + 16 * nt + lm;
    bv[nt] = bh[col];
    short8 fx;
#pragma unroll
    for (int j = 0; j < 8; ++j)
      fx[j] = f2bf(Wx[(size_t)(8 * l4 + j) * HID + col]);
    wxf[nt] = fx;
  }

  const size_t row0 = (size_t)blockIdx.x * GROWS;
#pragma unroll
  for (int mt = 0; mt < GROWS / 16; ++mt) {
    const size_t arow = row0 + mt * 16 + lm;
    const float* xp = x + arow * EMB + 8 * l4;
    f32x4 xf0 = *(const f32x4*)xp;
    f32x4 xf1 = *(const f32x4*)(xp + 4);
    short8 xa;
#pragma unroll
    for (int j = 0; j < 4; ++j) { xa[j] = f2bf(xf0[j]); xa[4 + j] = f2bf(xf1[j]); }
    f32x4 acc0 = {bv[0], bv[0], bv[0], bv[0]};
    f32x4 acc1 = {bv[1], bv[1], bv[1], bv[1]};
    acc0 = MFMA(xa, wxf[0], acc0);
    acc1 = MFMA(xa, wxf[1], acc1);
    unsigned short* op = xw + (row0 + mt * 16 + 4 * l4) * HID;
#pragma unroll
    for (int r = 0; r < 4; ++r) {
      op[(size_t)r * HID + colbase + lm]      = (unsigned short)f2bf(acc0[r]);
      op[(size_t)r * HID + colbase + 16 + lm] = (unsigned short)f2bf(acc1[r]);
    }
  }
}

// ------- Kernel 2: serial recurrence, 1 batch row/block, 8 waves x 16 cols -------
// All 16 A-rows broadcast the same h vector (acc[0] extraction — no row-mapping
// assumptions). 8 waves halve the per-wave MFMA issue on the serial chain
// (4 MFMAs/wave/step vs 8). 512 blocks -> 2 blocks/CU TLP, 4 waves/SIMD.
__global__ __launch_bounds__(512) void rnn_rec_kernel(
    const unsigned short* __restrict__ xw, const float* __restrict__ Wh,
    float* __restrict__ out) {
  __shared__ short hbuf[2][HID];

  const int tid = threadIdx.x;
  const int wid = tid >> 6;            // 0..7, owns cols [16w, 16w+16)
  const int lane = tid & 63;
  const int l4 = lane >> 4, lm = lane & 15;
  const int row0 = blockIdx.x;         // one batch row per block
  const int colbase = wid * 16;
  const int ocol = colbase + lm;       // lanes l4=0..3 duplicate each col

  for (int i = tid; i < 2 * HID; i += 512) ((short*)hbuf)[i] = 0;

  // B-frags: 1 n-tile x 4 k-chunks. lane: col = lm, k = 8*l4 + j.
  short8 whf[4];
#pragma unroll
  for (int kb = 0; kb < 4; ++kb) {
    short8 f;
#pragma unroll
    for (int j = 0; j < 8; ++j)
      f[j] = f2bf(Wh[(size_t)(32 * kb + 8 * l4 + j) * HID + ocol]);
    whf[kb] = f;
  }

  // byte offsets (fit u32: xw 67MB, out 134MB)
  const unsigned xw_off0  = ((unsigned)row0 * T_SEQ) * (HID * 2) + (unsigned)ocol * 2;
  const unsigned out_off0 = ((unsigned)row0 * T_SEQ) * (HID * 4) + (unsigned)ocol * 4;
  const unsigned short* xwb = xw;
  float* outb = out;
  float* hfinp = out + (size_t)512 * T_SEQ * HID + (size_t)row0 * HID + ocol;

  // read: wave-broadcast A-frags (16 lanes/address); write: own column
  // (4 lanes duplicate same addr+value — benign).
  const short* hr0 = &hbuf[0][8 * l4];
  const short* hr1 = &hbuf[1][8 * l4];
  short* hw0 = &hbuf[0][ocol];
  short* hw1 = &hbuf[1][ocol];

  // prologue: L0..L3 in flight (4 outstanding loads, 0 stores)
  unsigned xr0, xr1, xr2, xr3;
  asm volatile("global_load_ushort %0, %1, %2" : "=v"(xr0) : "v"(xw_off0 + 0u * 256u), "s"(xwb));
  asm volatile("global_load_ushort %0, %1, %2" : "=v"(xr1) : "v"(xw_off0 + 1u * 256u), "s"(xwb));
  asm volatile("global_load_ushort %0, %1, %2" : "=v"(xr2) : "v"(xw_off0 + 2u * 256u), "s"(xwb));
  asm volatile("global_load_ushort %0, %1, %2" : "=v"(xr3) : "v"(xw_off0 + 3u * 256u), "s"(xwb));

  float th_last = 0.f;

  __syncthreads();  // zero-init visible

  // Fixed vmem issue order per step: [wait vmcnt(WN) + in-asm reg read]
  // [refill load] ... [predicated store]. Store predicate l4==0 keeps 16
  // lanes active in EVERY wave -> the store always issues -> per-wave vmcnt
  // accounting identical to the verified round-9 schedule (peel 3/4/5/6,
  // steady 7 = 4 loads + 3 stores outstanding after L(t)).
#define RSTEP(T, PAR, WN, XR) do {                                               \
    const short* hb_ = (PAR) ? hr0 : hr1;   /* prev = PAR^1 */                   \
    short8 ah0 = *(const short8*)(hb_ + 0);                                      \
    short8 ah1 = *(const short8*)(hb_ + 32);                                     \
    short8 ah2 = *(const short8*)(hb_ + 64);                                     \
    short8 ah3 = *(const short8*)(hb_ + 96);                                     \
    unsigned xv_;                                                                \
    asm volatile("s_waitcnt vmcnt(" #WN ")\n\tv_mov_b32 %0, %1"                  \
                 : "=&v"(xv_) : "v"(XR));                                        \
    int tl_ = (T) + PF; if (tl_ > T_SEQ - 1) tl_ = T_SEQ - 1;                    \
    asm volatile("global_load_ushort %0, %1, %2"                                 \
                 : "=v"(XR) : "v"(xw_off0 + (unsigned)tl_ * 256u), "s"(xwb));    \
    const f32x4 z_ = {0.f, 0.f, 0.f, 0.f};                                       \
    f32x4 a_ = MFMA(ah0, whf[0], z_);                                            \
    f32x4 b_ = MFMA(ah2, whf[2], z_);                                            \
    a_ = MFMA(ah1, whf[1], a_);                                                  \
    b_ = MFMA(ah3, whf[3], b_);                                                  \
    float v_ = (a_[0] + b_[0]) + bf2f((unsigned short)xv_);                      \
    float th_ = tanh_fast(v_);                                                   \
    *((PAR) ? hw1 : hw0) = f2bf(th_);   /* cur = PAR; 1 ds_write_b16 */          \
    if (l4 == 0)                                                                 \
      asm volatile("global_store_dword %0, %1, %2"                               \
                   :: "v"(out_off0 + (unsigned)(T) * 512u), "v"(th_), "s"(outb));\
    th_last = th_;                                                               \
    asm volatile("s_waitcnt lgkmcnt(0)\n\ts_barrier" ::: "memory");              \
  } while (0)

  // peel: exact counts while the load/store pattern fills
  RSTEP(0, 0, 3, xr0);
  RSTEP(1, 1, 4, xr1);
  RSTEP(2, 0, 5, xr2);
  RSTEP(3, 1, 6, xr3);
  for (int tb = 4; tb < T_SEQ; tb += 4) {
    RSTEP(tb + 0, 0, 7, xr0);
    RSTEP(tb + 1, 1, 7, xr1);
    RSTEP(tb + 2, 0, 7, xr2);
    RSTEP(tb + 3, 1, 7, xr3);
  }
#undef RSTEP

  if (l4 == 0) *hfinp = th_last;  // final h (t = T-1), off the loop
}

// ---------------- Fallback (fused) if ws too small ----------------
__global__ __launch_bounds__(256) void rnn_fused_fallback(
    const float* __restrict__ x, const float* __restrict__ Wx,
    const float* __restrict__ Wh, const float* __restrict__ bh,
    float* __restrict__ out) {
  __shared__ short hbuf[2][2][LDSW];
  const int tid = threadIdx.x;
  const int wid = tid >> 6;
  const int lane = tid & 63;
  const int l4 = lane >> 4, lm = lane & 15;
  const int row0 = blockIdx.x * 2;
  const int colbase = wid * 32;
  for (int i = tid; i < 2 * 2 * LDSW; i += 256) ((short*)hbuf)[i] = 0;
  short8 whf[2][4]; short8 wxf[2]; float bv[2];
#pragma unroll
  for (int nt = 0; nt < 2; ++nt) {
    const int col = colbase + 16 * nt + lm;
    bv[nt] = bh[col];
#pragma unroll
    for (int kb = 0; kb < 4; ++kb) {
      short8 f;
#pragma unroll
      for (int j = 0; j < 8; ++j)
        f[j] = f2bf(Wh[(size_t)(32 * kb + 8 * l4 + j) * HID + col]);
      whf[nt][kb] = f;
    }
    short8 fx;
#pragma unroll
    for (int j = 0; j < 8; ++j)
      fx[j] = f2bf(Wx[(size_t)(8 * l4 + j) * HID + col]);
    wxf[nt] = fx;
  }
  const int xrow = row0 + (lm & 1);
  const float* xptr = x + (size_t)xrow * T_SEQ * EMB + 8 * l4;
  f32x4 xf0 = *(const f32x4*)(xptr);
  f32x4 xf1 = *(const f32x4*)(xptr + 4);
  const int rsel = l4 & 1, csel = l4 >> 1;
  const int ocol = colbase + 16 * csel + lm;
  float* outp = out + (size_t)(row0 + rsel) * T_SEQ * HID + ocol;
  float* hfinp = out + (size_t)512 * T_SEQ * HID + (size_t)(row0 + rsel) * HID + ocol;
  __syncthreads();
#pragma unroll 2
  for (int t = 0; t < T_SEQ; ++t) {
    const int cur = t & 1, prev = cur ^ 1;
    const short* hb = &hbuf[prev][lm & 1][0];
    short8 ah[4];
#pragma unroll
    for (int kb = 0; kb < 4; ++kb)
      ah[kb] = *(const short8*)(hb + 32 * kb + 8 * l4);
    short8 xa;
#pragma unroll
    for (int j = 0; j < 4; ++j) { xa[j] = f2bf(xf0[j]); xa[4 + j] = f2bf(xf1[j]); }
    if (t + 1 < T_SEQ) {
      xf0 = *(const f32x4*)(xptr + (size_t)(t + 1) * EMB);
      xf1 = *(const f32x4*)(xptr + (size_t)(t + 1) * EMB + 4);
    }
    f32x4 acc0a = {bv[0], bv[0], bv[0], bv[0]};
    f32x4 acc1a = {bv[1], bv[1], bv[1], bv[1]};
    f32x4 acc0b = {0.f, 0.f, 0.f, 0.f};
    f32x4 acc1b = {0.f, 0.f, 0.f, 0.f};
    acc0a = MFMA(xa, wxf[0], acc0a);
    acc1a = MFMA(xa, wxf[1], acc1a);
    acc0a = MFMA(ah[0], whf[0][0], acc0a);
    acc1a = MFMA(ah[0], whf[1][0], acc1a);
    acc0a = MFMA(ah[1], whf[0][1], acc0a);
    acc1a = MFMA(ah[1], whf[1][1], acc1a);
    acc0b = MFMA(ah[2], whf[0][2], acc0b);
    acc1b = MFMA(ah[2], whf[1][2], acc1b);
    acc0b = MFMA(ah[3], whf[0][3], acc0b);
    acc1b = MFMA(ah[3], whf[1][3], acc1b);
    float v0 = (rsel ? acc0a[1] : acc0a[0]) + (rsel ? acc0b[1] : acc0b[0]);
    float v1 = (rsel ? acc1a[1] : acc1a[0]) + (rsel ? acc1b[1] : acc1b[0]);
    float v = csel ? v1 : v0;
    float th = tanh_fast(v);
    hbuf[cur][rsel][ocol] = f2bf(th);
    *outp = th; outp += HID;
    if (t == T_SEQ - 1) *hfinp = th;
    asm volatile("s_waitcnt lgkmcnt(0)\n\ts_barrier" ::: "memory");
  }
}

extern "C" void kernel_launch(void* const* d_in, const int* in_sizes, int n_in,
                              void* d_out, int out_size, void* d_ws, size_t ws_size,
                              hipStream_t stream) {
  const float* x  = (const float*)d_in[0];
  const float* Wx = (const float*)d_in[1];
  const float* Wh = (const float*)d_in[2];
  const float* bh = (const float*)d_in[3];
  float* out = (float*)d_out;
  (void)in_sizes; (void)n_in; (void)out_size;

  const size_t need = (size_t)512 * T_SEQ * HID * sizeof(unsigned short);  // 67 MB
  if (ws_size >= need) {
    unsigned short* xw = (unsigned short*)d_ws;
    xw_gemm_kernel<<<(512 * T_SEQ) / GROWS, 256, 0, stream>>>(x, Wx, bh, xw);
    rnn_rec_kernel<<<512, 512, 0, stream>>>(xw, Wh, out);
  } else {
    rnn_fused_fallback<<<256, 256, 0, stream>>>(x, Wx, Wh, bh, out);
  }
}

// Round 15
// 136.731 us; speedup vs baseline: 1.1361x; 1.1361x over previous
//
#include <hip/hip_runtime.h>

#define T_SEQ 512
#define EMB 32
#define HID 128
#define BB 2          // batch rows per block -> 256 blocks, 1 block/CU
#define LDSW 160      // h row stride in bf16 elems
#define TCH 128       // x timesteps per LDS chunk (4 chunks total)

typedef __attribute__((ext_vector_type(8))) short short8;   // 8 bf16
typedef __attribute__((ext_vector_type(4))) short short4v;  // 4 bf16
typedef __attribute__((ext_vector_type(4))) float f32x4;

__device__ __forceinline__ short f2bf(float f) {
  union { float f; unsigned u; } v; v.f = f;
  unsigned r = (v.u + 0x7FFFu + ((v.u >> 16) & 1u)) >> 16;  // RNE
  return (short)r;
}

__device__ __forceinline__ float tanh_fast(float a) {
  float e = __expf(2.0f * a);
  return 1.0f - 2.0f * __builtin_amdgcn_rcpf(e + 1.0f);
}

#define MFMA(a, b, c) __builtin_amdgcn_mfma_f32_16x16x32_bf16((a), (b), (c), 0, 0, 0)

// Single fused kernel. x is staged into LDS as bf16 in 128-step chunks
// (plain HIP loads + __syncthreads, 4x per kernel). The serial step loop has
// ZERO vmem loads: 5 ds_read_b128 + 10 MFMA + tail + 1 ds_write + 1 asm
// store + lgkmcnt(0)/s_barrier. No vmcnt waits anywhere in the loop.
// (The R11/R12 in-loop asm dwordx4 load ring core-dumped twice - reverted.)
__global__ __launch_bounds__(256) void rnn_fused_kernel(
    const float* __restrict__ x, const float* __restrict__ Wx,
    const float* __restrict__ Wh, const float* __restrict__ bh,
    float* __restrict__ out) {
  __shared__ short hbuf[2][BB][LDSW];          // 1280 B
  __shared__ short xlds[TCH][BB][EMB];         // 16 KB: [t&127][row][e]

  const int tid = threadIdx.x;
  const int wid = tid >> 6;        // wave 0..3, owns cols [32w, 32w+32)
  const int lane = tid & 63;
  const int l4 = lane >> 4, lm = lane & 15;
  const int row0 = blockIdx.x * BB;
  const int colbase = wid * 32;

  for (int i = tid; i < 2 * BB * LDSW; i += 256) ((short*)hbuf)[i] = 0;

  // ---- weights into registers (B-frag: col = lane&15, k = 8*(lane>>4)+j) ----
  short8 whf[2][4]; short8 wxf[2]; float bv[2];
#pragma unroll
  for (int nt = 0; nt < 2; ++nt) {
    const int col = colbase + 16 * nt + lm;
    bv[nt] = bh[col];
#pragma unroll
    for (int kb = 0; kb < 4; ++kb) {
      short8 f;
#pragma unroll
      for (int j = 0; j < 8; ++j)
        f[j] = f2bf(Wh[(size_t)(32 * kb + 8 * l4 + j) * HID + col]);
      whf[nt][kb] = f;
    }
    short8 fx;
#pragma unroll
    for (int j = 0; j < 8; ++j)
      fx[j] = f2bf(Wx[(size_t)(8 * l4 + j) * HID + col]);
    wxf[nt] = fx;
  }

  const int rsel = l4 & 1;         // batch row parity this lane outputs
  const int csel = l4 >> 1;        // which 16-col tile
  const int ocol = colbase + 16 * csel + lm;

  const unsigned out_off0 =
      ((unsigned)(row0 + rsel) * T_SEQ) * (HID * 4) + (unsigned)ocol * 4;
  float* outb = out;
  float* hfinp = out + (size_t)512 * T_SEQ * HID + (size_t)(row0 + rsel) * HID + ocol;

  // LDS ptrs: h A-frag read row = lm&1 (k-offset 8*l4 folded); x A-frag read
  // row = lm&1, elems 8*l4..+7 (8 distinct 16B lines across 128 B: conflict-free)
  const short* hr0 = &hbuf[0][lm & 1][8 * l4];
  const short* hr1 = &hbuf[1][lm & 1][8 * l4];
  short* hw0 = &hbuf[0][rsel][ocol];
  short* hw1 = &hbuf[1][rsel][ocol];
  const short* xbase = &xlds[0][lm & 1][8 * l4];

  const float* xsrc = x + (size_t)row0 * T_SEQ * EMB;  // 2 contiguous rows

  const f32x4 z_  = {0.f, 0.f, 0.f, 0.f};
  const f32x4 cb0 = {bv[0], bv[0], bv[0], bv[0]};   // bias as x-MFMA C
  const f32x4 cb1 = {bv[1], bv[1], bv[1], bv[1]};

  float th_last = 0.f;

  // Per step: 3 independent MFMA chains (p: x-proj depth 1, a/b: depth 2).
#define RSTEP(T, PAR) do {                                                       \
    const short* hb_ = (PAR) ? hr0 : hr1;   /* prev = PAR^1 */                   \
    short8 ah0 = *(const short8*)(hb_ + 0);                                      \
    short8 ah1 = *(const short8*)(hb_ + 32);                                     \
    short8 ah2 = *(const short8*)(hb_ + 64);                                     \
    short8 ah3 = *(const short8*)(hb_ + 96);                                     \
    short8 xa = *(const short8*)(xbase + ((T) & (TCH - 1)) * (BB * EMB));        \
    f32x4 p0 = MFMA(xa, wxf[0], cb0);                                            \
    f32x4 p1 = MFMA(xa, wxf[1], cb1);                                            \
    f32x4 a0 = MFMA(ah0, whf[0][0], z_);                                         \
    f32x4 a1 = MFMA(ah0, whf[1][0], z_);                                         \
    f32x4 b0 = MFMA(ah2, whf[0][2], z_);                                         \
    f32x4 b1 = MFMA(ah2, whf[1][2], z_);                                         \
    a0 = MFMA(ah1, whf[0][1], a0);                                               \
    a1 = MFMA(ah1, whf[1][1], a1);                                               \
    b0 = MFMA(ah3, whf[0][3], b0);                                               \
    b1 = MFMA(ah3, whf[1][3], b1);                                               \
    float vP0 = rsel ? p0[1] : p0[0];                                            \
    float vA0 = rsel ? a0[1] : a0[0];                                            \
    float vB0 = rsel ? b0[1] : b0[0];                                            \
    float vP1 = rsel ? p1[1] : p1[0];                                            \
    float vA1 = rsel ? a1[1] : a1[0];                                            \
    float vB1 = rsel ? b1[1] : b1[0];                                            \
    float v_ = csel ? ((vP1 + vA1) + vB1) : ((vP0 + vA0) + vB0);                 \
    float th_ = tanh_fast(v_);                                                   \
    *((PAR) ? hw1 : hw0) = f2bf(th_);   /* cur = PAR; 1 ds_write_b16 */          \
    asm volatile("global_store_dword %0, %1, %2"                                 \
                 :: "v"(out_off0 + (unsigned)(T) * 512u), "v"(th_), "s"(outb));  \
    th_last = th_;                                                               \
    asm volatile("s_waitcnt lgkmcnt(0)\n\ts_barrier" ::: "memory");              \
  } while (0)

  for (int tb = 0; tb < T_SEQ; tb += TCH) {
    // ---- stage chunk [tb, tb+TCH) of x into LDS as bf16 ----
    // (prev chunk's last RSTEP barrier guarantees all reads of xlds are done)
#pragma unroll
    for (int k = 0; k < (BB * TCH * EMB / 4) / 256; ++k) {  // 8 float4 / thread
      const int flat4 = tid + k * 256;
      const int e4 = flat4 & 7;             // which float4 within a t-row
      const int tt = (flat4 >> 3) & (TCH - 1);
      const int r  = flat4 >> 10;           // 0..1
      const f32x4 v4 = *(const f32x4*)(xsrc + (size_t)r * T_SEQ * EMB +
                                       (size_t)(tb + tt) * EMB + e4 * 4);
      short4v s4;
      s4[0] = f2bf(v4[0]); s4[1] = f2bf(v4[1]);
      s4[2] = f2bf(v4[2]); s4[3] = f2bf(v4[3]);
      *(short4v*)&xlds[tt][r][e4 * 4] = s4;
    }
    __syncthreads();  // chunk visible (also covers hbuf init before chunk 0)

#pragma unroll 4
    for (int t = tb; t < tb + TCH; t += 2) {
      RSTEP(t + 0, 0);
      RSTEP(t + 1, 1);
    }
  }
#undef RSTEP

  *hfinp = th_last;  // final h (t = T-1), off the loop
}

extern "C" void kernel_launch(void* const* d_in, const int* in_sizes, int n_in,
                              void* d_out, int out_size, void* d_ws, size_t ws_size,
                              hipStream_t stream) {
  const float* x  = (const float*)d_in[0];
  const float* Wx = (const float*)d_in[1];
  const float* Wh = (const float*)d_in[2];
  const float* bh = (const float*)d_in[3];
  float* out = (float*)d_out;
  (void)in_sizes; (void)n_in; (void)out_size; (void)d_ws; (void)ws_size;
  rnn_fused_kernel<<<512 / BB, 256, 0, stream>>>(x, Wx, Wh, bh, out);
}